// Round 1
// baseline (874.896 us; speedup 1.0000x reference)
//
#include <hip/hip_runtime.h>
#include <math.h>

#define HEADS 4
#define NEG_SLOPE 0.2f

// ---------------- workspace layout (bytes) ----------------
// max live ~106.3 MB
static constexpr size_t OFF_H1   = 0;           // 51,200,000  (h1; later h2 + out2)
static constexpr size_t OFF_OUT1 = 51200000;    // 51,200,000
static constexpr size_t OFF_AS   = 102400000;   // 800,000
static constexpr size_t OFF_AD   = 103200000;   // 800,000
static constexpr size_t OFF_RP   = 104000000;   // 200,064 (row_ptr, N+1 ints)
static constexpr size_t OFF_CUR  = 104200064;   // 200,064 (cursor)
static constexpr size_t OFF_CNT  = 104400128;   // 200,064 (counts)
static constexpr size_t OFF_CSR  = 104600192;   // 1,600,000 (csr src ids)
static constexpr size_t OFF_SUM  = 106200192;   // 16,384 (pool sums 64x64)
static constexpr size_t OFF_GCNT = 106216576;   // 256   (pool counts)

// ---------------- helpers ----------------
__device__ __forceinline__ float4 f4add(float4 a, float4 b) {
    return make_float4(a.x + b.x, a.y + b.y, a.z + b.z, a.w + b.w);
}
__device__ __forceinline__ float4 f4sub(float4 a, float4 b) {
    return make_float4(a.x - b.x, a.y - b.y, a.z - b.z, a.w - b.w);
}
__device__ __forceinline__ float4 f4max(float4 a, float4 b) {
    return make_float4(fmaxf(a.x, b.x), fmaxf(a.y, b.y), fmaxf(a.z, b.z), fmaxf(a.w, b.w));
}
__device__ __forceinline__ float lrelu(float x) { return x > 0.f ? x : NEG_SLOPE * x; }
__device__ __forceinline__ float4 f4lrelu(float4 a) {
    return make_float4(lrelu(a.x), lrelu(a.y), lrelu(a.z), lrelu(a.w));
}
__device__ __forceinline__ float4 f4exp(float4 a) {
    return make_float4(__expf(a.x), __expf(a.y), __expf(a.z), __expf(a.w));
}
__device__ __forceinline__ float4 shfl4(float4 v, int j) {
    return make_float4(__shfl(v.x, j), __shfl(v.y, j), __shfl(v.z, j), __shfl(v.w, j));
}
__device__ __forceinline__ float pickh(float4 v, int head) {
    float r = v.x;
    r = head == 1 ? v.y : r;
    r = head == 2 ? v.z : r;
    r = head == 3 ? v.w : r;
    return r;
}

// ---------------- GEMM with GAT-alpha epilogue ----------------
// C[M,N] = A[M,K] @ B[K,N]; also alpha_s[m,h] += sum_c C[m,h*CPH+c]*avec_s[h,c]
// BK=32 fixed. 256 threads. micro-tile 8x8. As stored transposed [k][m] (pad),
// Bs packed per (4k-chunk, 8-col group) with XOR slot swizzle -> conflict-free b128.
template<int BM, int BN, int CPH>
__global__ __launch_bounds__(256, 2)
void gemm_gat(const float* __restrict__ A, const float* __restrict__ Bg,
              float* __restrict__ C,
              const float* __restrict__ avec_s, const float* __restrict__ avec_d,
              float* __restrict__ alpha_s, float* __restrict__ alpha_d,
              int M, int K, int N)
{
    constexpr int BK  = 32;
    constexpr int BMP = BM + 4;
    constexpr int NCG = BN / 8;   // 8-col groups
    constexpr int NTC = BN / 8;
    static_assert((BM / 8) * (BN / 8) == 256, "thread mapping");

    __shared__ float  As[BK * BMP];
    __shared__ float4 Bs[(BK / 4) * NCG * 8];

    const int tid = threadIdx.x;
    const int tr  = tid / NTC;
    const int tc  = tid % NTC;
    const int m0  = blockIdx.x * BM;
    const int n0  = blockIdx.y * BN;
    const int r0  = tr * 8;

    float acc[8][8];
#pragma unroll
    for (int i = 0; i < 8; ++i)
#pragma unroll
        for (int j = 0; j < 8; ++j) acc[i][j] = 0.f;

    for (int kb = 0; kb < K; kb += BK) {
        // stage A tile [BM][BK] -> As[k][m] (transposed)
        constexpr int APASS = (BM * (BK / 4)) / 256;
#pragma unroll
        for (int p = 0; p < APASS; ++p) {
            int id  = p * 256 + tid;
            int mt  = id / (BK / 4);
            int kq4 = (id % (BK / 4)) * 4;
            int row = m0 + mt;
            row = row < M ? row : M - 1;
            float4 v = *(const float4*)(A + (size_t)row * K + kb + kq4);
            As[(kq4 + 0) * BMP + mt] = v.x;
            As[(kq4 + 1) * BMP + mt] = v.y;
            As[(kq4 + 2) * BMP + mt] = v.z;
            As[(kq4 + 3) * BMP + mt] = v.w;
        }
        // stage B tile [BK][BN] -> packed Bs
        constexpr int BPASS = (BK * (BN / 4)) / 256;
#pragma unroll
        for (int p = 0; p < BPASS; ++p) {
            int id = p * 256 + tid;
            int kt = id / (BN / 4);
            int c4 = id % (BN / 4);
            float4 v = *(const float4*)(Bg + (size_t)(kb + kt) * N + n0 + c4 * 4);
            int g     = c4 >> 1;
            int hhalf = c4 & 1;
            int f     = (kt & 3) * 2 + hhalf;
            int slot  = f ^ (g & 7);
            Bs[(((kt >> 2) * NCG) + g) * 8 + slot] = v;
        }
        __syncthreads();

        for (int kk = 0; kk < BK / 4; ++kk) {
#pragma unroll
            for (int kq = 0; kq < 4; ++kq) {
                int k = kk * 4 + kq;
                float4 a0 = *(const float4*)(&As[k * BMP + r0]);
                float4 a1 = *(const float4*)(&As[k * BMP + r0 + 4]);
                float4 b0 = Bs[(kk * NCG + tc) * 8 + ((kq * 2 + 0) ^ (tc & 7))];
                float4 b1 = Bs[(kk * NCG + tc) * 8 + ((kq * 2 + 1) ^ (tc & 7))];
                float av[8] = {a0.x, a0.y, a0.z, a0.w, a1.x, a1.y, a1.z, a1.w};
                float bv[8] = {b0.x, b0.y, b0.z, b0.w, b1.x, b1.y, b1.z, b1.w};
#pragma unroll
                for (int i = 0; i < 8; ++i)
#pragma unroll
                    for (int j = 0; j < 8; ++j) acc[i][j] += av[i] * bv[j];
            }
        }
        __syncthreads();
    }

    // epilogue: store C + alpha partial dots
    const int cb   = n0 + tc * 8;       // first col of this thread (8 cols, one head)
    const int head = cb / CPH;
    const int ci0  = cb % CPH;
    float asv[8], adv[8];
#pragma unroll
    for (int j = 0; j < 8; ++j) {
        asv[j] = avec_s[head * CPH + ci0 + j];
        adv[j] = avec_d[head * CPH + ci0 + j];
    }
#pragma unroll
    for (int i = 0; i < 8; ++i) {
        int row = m0 + r0 + i;
        if (row < M) {
            float4 c0 = make_float4(acc[i][0], acc[i][1], acc[i][2], acc[i][3]);
            float4 c1 = make_float4(acc[i][4], acc[i][5], acc[i][6], acc[i][7]);
            *(float4*)(C + (size_t)row * N + cb)     = c0;
            *(float4*)(C + (size_t)row * N + cb + 4) = c1;
            float ps = 0.f, pd = 0.f;
#pragma unroll
            for (int j = 0; j < 8; ++j) {
                ps += acc[i][j] * asv[j];
                pd += acc[i][j] * adv[j];
            }
            atomicAdd(&alpha_s[row * HEADS + head], ps);
            atomicAdd(&alpha_d[row * HEADS + head], pd);
        }
    }
}

// ---------------- CSR build ----------------
__global__ void count_kernel(const int* __restrict__ dst, int* __restrict__ counts, int E)
{
    int e = blockIdx.x * 256 + threadIdx.x;
    if (e < E) atomicAdd(&counts[dst[e]], 1);
}

__global__ void scatter_kernel(const int* __restrict__ src, const int* __restrict__ dst,
                               int* __restrict__ cursor, int* __restrict__ csr, int E)
{
    int e = blockIdx.x * 256 + threadIdx.x;
    if (e < E) {
        int d   = dst[e];
        int pos = atomicAdd(&cursor[d], 1);
        csr[pos] = src[e];
    }
}

// single-block exclusive scan over n counts -> row_ptr[0..n], cursor copy
__global__ __launch_bounds__(1024)
void scan_kernel(const int* __restrict__ counts, int* __restrict__ row_ptr,
                 int* __restrict__ cursor, int n)
{
    __shared__ int wsum[16];
    __shared__ int running;
    const int t = threadIdx.x, lane = t & 63, w = t >> 6;
    if (t == 0) running = 0;
    __syncthreads();
    for (int base = 0; base < n; base += 1024) {
        int i = base + t;
        int v = (i < n) ? counts[i] : 0;
        int x = v;
#pragma unroll
        for (int d = 1; d < 64; d <<= 1) {
            int y = __shfl_up(x, d);
            if (lane >= d) x += y;
        }
        if (lane == 63) wsum[w] = x;
        __syncthreads();
        if (t < 16) {
            int s = wsum[t];
#pragma unroll
            for (int d = 1; d < 16; d <<= 1) {
                int y = __shfl_up(s, d);
                if (t >= d) s += y;
            }
            wsum[t] = s;
        }
        __syncthreads();
        int wbase = (w > 0) ? wsum[w - 1] : 0;
        int excl  = running + wbase + x - v;
        if (i < n) {
            row_ptr[i] = excl;
            cursor[i]  = excl;
        }
        int total = wsum[15];
        __syncthreads();
        if (t == 0) running += total;
        __syncthreads();
    }
    if (t == 0) row_ptr[n] = running;
}

// ---------------- GAT softmax + aggregation ----------------
// one wave per destination node; includes PyG self-loop; writes relu(out + bias)
template<int CH>
__global__ __launch_bounds__(256)
void gat_agg(const float* __restrict__ h, const float* __restrict__ alpha_s,
             const float* __restrict__ alpha_d, const int* __restrict__ row_ptr,
             const int* __restrict__ csr_src, const float* __restrict__ bias,
             float* __restrict__ out, int n)
{
    const int wid  = threadIdx.x >> 6;
    const int lane = threadIdx.x & 63;
    const int node = blockIdx.x * 4 + wid;
    if (node >= n) return;
    const int head = lane >> 4;             // CH=256: c0=lane*4, head=c0/64; CH=64: c0=lane, head=c0/16
    const int p0 = row_ptr[node], p1 = row_ptr[node + 1];
    const int deg = p1 - p0;

    const float4 asn = *(const float4*)(alpha_s + (size_t)node * 4);
    const float4 adn = *(const float4*)(alpha_d + (size_t)node * 4);
    float4 eself = f4lrelu(f4add(asn, adn));
    float4 m = eself;

    // pass 1: per-head max over incoming edges
    for (int ch = 0; ch < deg; ch += 64) {
        int cnt = min(64, deg - ch);
        int sl = (lane < cnt) ? csr_src[p0 + ch + lane] : 0;
        float4 al = *(const float4*)(alpha_s + (size_t)sl * 4);
        for (int j = 0; j < cnt; ++j) {
            float4 aj = shfl4(al, j);
            m = f4max(m, f4lrelu(f4add(aj, adn)));
        }
    }

    // pass 2: denom + unnormalized weighted sum (self-loop first)
    float4 den = f4exp(f4sub(eself, m));
    float  wse = pickh(den, head);
    float4 acc4 = make_float4(0.f, 0.f, 0.f, 0.f);
    float  acc1 = 0.f;
    if constexpr (CH == 256) {
        float4 hv = *(const float4*)(h + (size_t)node * CH + lane * 4);
        acc4 = make_float4(wse * hv.x, wse * hv.y, wse * hv.z, wse * hv.w);
    } else {
        acc1 = wse * h[(size_t)node * CH + lane];
    }
    for (int ch = 0; ch < deg; ch += 64) {
        int cnt = min(64, deg - ch);
        int sl = (lane < cnt) ? csr_src[p0 + ch + lane] : 0;
        float4 al = *(const float4*)(alpha_s + (size_t)sl * 4);
        for (int j = 0; j < cnt; ++j) {
            int    sj = __shfl(sl, j);
            float4 aj = shfl4(al, j);
            float4 w4 = f4exp(f4sub(f4lrelu(f4add(aj, adn)), m));
            den = f4add(den, w4);
            float w = pickh(w4, head);
            if constexpr (CH == 256) {
                float4 hv = *(const float4*)(h + (size_t)sj * CH + lane * 4);
                acc4.x += w * hv.x; acc4.y += w * hv.y;
                acc4.z += w * hv.z; acc4.w += w * hv.w;
            } else {
                acc1 += w * h[(size_t)sj * CH + lane];
            }
        }
    }

    float invd = 1.0f / (pickh(den, head) + 1e-16f);
    if constexpr (CH == 256) {
        int c0 = lane * 4;
        float4 o;
        o.x = fmaxf(acc4.x * invd + bias[c0 + 0], 0.f);
        o.y = fmaxf(acc4.y * invd + bias[c0 + 1], 0.f);
        o.z = fmaxf(acc4.z * invd + bias[c0 + 2], 0.f);
        o.w = fmaxf(acc4.w * invd + bias[c0 + 3], 0.f);
        *(float4*)(out + (size_t)node * CH + c0) = o;
    } else {
        out[(size_t)node * CH + lane] = fmaxf(acc1 * invd + bias[lane], 0.f);
    }
}

// ---------------- global mean pool + FC ----------------
__global__ void pool_kernel(const float* __restrict__ feat, const int* __restrict__ batch,
                            float* __restrict__ sums, float* __restrict__ gcnt, int n)
{
    int gid = blockIdx.x * 256 + threadIdx.x;
    int nidx = gid >> 4, q = gid & 15;
    if (nidx >= n) return;
    int g = batch[nidx];
    float4 v = *(const float4*)(feat + (size_t)nidx * 64 + q * 4);
    atomicAdd(&sums[g * 64 + q * 4 + 0], v.x);
    atomicAdd(&sums[g * 64 + q * 4 + 1], v.y);
    atomicAdd(&sums[g * 64 + q * 4 + 2], v.z);
    atomicAdd(&sums[g * 64 + q * 4 + 3], v.w);
    if (q == 0) atomicAdd(&gcnt[g], 1.0f);
}

__global__ void final_fc(const float* __restrict__ sums, const float* __restrict__ gcnt,
                         const float* __restrict__ Wfc, const float* __restrict__ bfc,
                         float* __restrict__ out)
{
    int t = threadIdx.x;
    if (t >= 64 * 2) return;
    int g = t >> 1, o = t & 1;
    float inv = 1.0f / fmaxf(gcnt[g], 1.0f);
    float acc = bfc[o];
    for (int c = 0; c < 64; ++c)
        acc += sums[g * 64 + c] * inv * Wfc[c * 2 + o];
    out[g * 2 + o] = acc;
}

// ---------------- launch ----------------
extern "C" void kernel_launch(void* const* d_in, const int* in_sizes, int n_in,
                              void* d_out, int out_size, void* d_ws, size_t ws_size,
                              hipStream_t stream)
{
    const float* x    = (const float*)d_in[0];
    const int*   ei   = (const int*)d_in[1];
    const int*   batch= (const int*)d_in[2];
    const float* W1   = (const float*)d_in[3];
    const float* as1  = (const float*)d_in[4];
    const float* ad1  = (const float*)d_in[5];
    const float* b1   = (const float*)d_in[6];
    const float* W2   = (const float*)d_in[7];
    const float* as2  = (const float*)d_in[8];
    const float* ad2  = (const float*)d_in[9];
    const float* b2   = (const float*)d_in[10];
    const float* Wfc  = (const float*)d_in[11];
    const float* bfc  = (const float*)d_in[12];
    float* out = (float*)d_out;

    const int N = in_sizes[2];          // 50000 nodes
    const int E = in_sizes[1] / 27;     // 400000 edges
    const int F = in_sizes[0] / N;      // 128

    char* ws = (char*)d_ws;
    float* h1    = (float*)(ws + OFF_H1);
    float* out1  = (float*)(ws + OFF_OUT1);
    float* h2    = (float*)(ws + OFF_H1);              // reuse (h1 dead after agg1)
    float* out2  = (float*)(ws + OFF_H1 + 12800000);
    float* al_s  = (float*)(ws + OFF_AS);
    float* al_d  = (float*)(ws + OFF_AD);
    int*   rp    = (int*)(ws + OFF_RP);
    int*   cur   = (int*)(ws + OFF_CUR);
    int*   cnt   = (int*)(ws + OFF_CNT);
    int*   csr   = (int*)(ws + OFF_CSR);
    float* sums  = (float*)(ws + OFF_SUM);
    float* gcnt  = (float*)(ws + OFF_GCNT);

    const int egrid = (E + 255) / 256;

    // ---- layer 1 ----
    hipMemsetAsync(al_s, 0, (size_t)N * HEADS * sizeof(float), stream);
    hipMemsetAsync(al_d, 0, (size_t)N * HEADS * sizeof(float), stream);
    {
        dim3 g((N + 127) / 128, 256 / 128);
        gemm_gat<128, 128, 64><<<g, 256, 0, stream>>>(x, W1, h1, as1, ad1, al_s, al_d,
                                                      N, F, HEADS * 64);
    }
    hipMemsetAsync(cnt, 0, (size_t)N * sizeof(int), stream);
    count_kernel<<<egrid, 256, 0, stream>>>(ei + 26 * (size_t)E, cnt, E);
    scan_kernel<<<1, 1024, 0, stream>>>(cnt, rp, cur, N);
    scatter_kernel<<<egrid, 256, 0, stream>>>(ei + 17 * (size_t)E, ei + 26 * (size_t)E, cur, csr, E);
    gat_agg<256><<<(N + 3) / 4, 256, 0, stream>>>(h1, al_s, al_d, rp, csr, b1, out1, N);

    // ---- layer 2 ----
    hipMemsetAsync(al_s, 0, (size_t)N * HEADS * sizeof(float), stream);
    hipMemsetAsync(al_d, 0, (size_t)N * HEADS * sizeof(float), stream);
    {
        dim3 g((N + 255) / 256, 1);
        gemm_gat<256, 64, 16><<<g, 256, 0, stream>>>(out1, W2, h2, as2, ad2, al_s, al_d,
                                                     N, HEADS * 64, HEADS * 16);
    }
    hipMemsetAsync(cnt, 0, (size_t)N * sizeof(int), stream);
    count_kernel<<<egrid, 256, 0, stream>>>(ei + 16 * (size_t)E, cnt, E);
    scan_kernel<<<1, 1024, 0, stream>>>(cnt, rp, cur, N);
    scatter_kernel<<<egrid, 256, 0, stream>>>(ei + 15 * (size_t)E, ei + 16 * (size_t)E, cur, csr, E);
    gat_agg<64><<<(N + 3) / 4, 256, 0, stream>>>(h2, al_s, al_d, rp, csr, b2, out2, N);

    // ---- pool + fc ----
    hipMemsetAsync(sums, 0, 64 * 64 * sizeof(float), stream);
    hipMemsetAsync(gcnt, 0, 64 * sizeof(float), stream);
    pool_kernel<<<(N * 16 + 255) / 256, 256, 0, stream>>>(out2, batch, sums, gcnt, N);
    final_fc<<<1, 128, 0, stream>>>(sums, gcnt, Wfc, bfc, out);
}

// Round 2
// 441.230 us; speedup vs baseline: 1.9829x; 1.9829x over previous
//
#include <hip/hip_runtime.h>
#include <math.h>

#define HEADS 4
#define NEG_SLOPE 0.2f

// ---------------- workspace layout (bytes) ----------------
static constexpr size_t OFF_H1   = 0;           // 51,200,000  (h1; later h2 + out2)
static constexpr size_t OFF_OUT1 = 51200000;    // 51,200,000
static constexpr size_t OFF_AS   = 102400000;   // 800,000
static constexpr size_t OFF_AD   = 103200000;   // 800,000
static constexpr size_t OFF_RP   = 104000000;   // 200,064 (row_ptr, N+1 ints)
static constexpr size_t OFF_CUR  = 104200064;   // 200,064 (cursor)
static constexpr size_t OFF_CNT  = 104400128;   // 200,064 (counts)
static constexpr size_t OFF_CSR  = 104600192;   // 1,600,000 (csr src ids)
static constexpr size_t OFF_STRT = 106200192;   // 260 (graph starts, 65 ints)

// ---------------- helpers ----------------
__device__ __forceinline__ float4 f4add(float4 a, float4 b) {
    return make_float4(a.x + b.x, a.y + b.y, a.z + b.z, a.w + b.w);
}
__device__ __forceinline__ float4 f4sub(float4 a, float4 b) {
    return make_float4(a.x - b.x, a.y - b.y, a.z - b.z, a.w - b.w);
}
__device__ __forceinline__ float4 f4max(float4 a, float4 b) {
    return make_float4(fmaxf(a.x, b.x), fmaxf(a.y, b.y), fmaxf(a.z, b.z), fmaxf(a.w, b.w));
}
__device__ __forceinline__ float lrelu(float x) { return x > 0.f ? x : NEG_SLOPE * x; }
__device__ __forceinline__ float4 f4lrelu(float4 a) {
    return make_float4(lrelu(a.x), lrelu(a.y), lrelu(a.z), lrelu(a.w));
}
__device__ __forceinline__ float4 f4exp(float4 a) {
    return make_float4(__expf(a.x), __expf(a.y), __expf(a.z), __expf(a.w));
}
__device__ __forceinline__ float4 shfl4(float4 v, int j) {
    return make_float4(__shfl(v.x, j), __shfl(v.y, j), __shfl(v.z, j), __shfl(v.w, j));
}
__device__ __forceinline__ float pickh(float4 v, int head) {
    float r = v.x;
    r = head == 1 ? v.y : r;
    r = head == 2 ? v.z : r;
    r = head == 3 ? v.w : r;
    return r;
}

// ---------------- GEMM with GAT-alpha epilogue ----------------
// C[M,N] = A[M,K] @ B[K,N]; alpha_{s,d}[m,h] = sum_c C[m,h*CPH+c]*avec_{s,d}[h,c]
// Alpha epilogue: the CPH/8 threads covering one (row,head) are consecutive
// lanes (same tr) -> shfl_down tree -> ONE plain store per (row,head), no atomics.
template<int BM, int BN, int CPH>
__global__ __launch_bounds__(256, 2)
void gemm_gat(const float* __restrict__ A, const float* __restrict__ Bg,
              float* __restrict__ C,
              const float* __restrict__ avec_s, const float* __restrict__ avec_d,
              float* __restrict__ alpha_s, float* __restrict__ alpha_d,
              int M, int K, int N)
{
    constexpr int BK  = 32;
    constexpr int BMP = BM + 4;
    constexpr int NCG = BN / 8;   // 8-col groups
    constexpr int NTC = BN / 8;
    constexpr int GRP = CPH / 8;  // threads per (row,head)
    static_assert((BM / 8) * (BN / 8) == 256, "thread mapping");

    __shared__ float  As[BK * BMP];
    __shared__ float4 Bs[(BK / 4) * NCG * 8];

    const int tid = threadIdx.x;
    const int tr  = tid / NTC;
    const int tc  = tid % NTC;
    const int m0  = blockIdx.x * BM;
    const int n0  = blockIdx.y * BN;
    const int r0  = tr * 8;

    float acc[8][8];
#pragma unroll
    for (int i = 0; i < 8; ++i)
#pragma unroll
        for (int j = 0; j < 8; ++j) acc[i][j] = 0.f;

    for (int kb = 0; kb < K; kb += BK) {
        // stage A tile [BM][BK] -> As[k][m] (transposed)
        constexpr int APASS = (BM * (BK / 4)) / 256;
#pragma unroll
        for (int p = 0; p < APASS; ++p) {
            int id  = p * 256 + tid;
            int mt  = id / (BK / 4);
            int kq4 = (id % (BK / 4)) * 4;
            int row = m0 + mt;
            row = row < M ? row : M - 1;
            float4 v = *(const float4*)(A + (size_t)row * K + kb + kq4);
            As[(kq4 + 0) * BMP + mt] = v.x;
            As[(kq4 + 1) * BMP + mt] = v.y;
            As[(kq4 + 2) * BMP + mt] = v.z;
            As[(kq4 + 3) * BMP + mt] = v.w;
        }
        // stage B tile [BK][BN] -> packed Bs (XOR slot swizzle)
        constexpr int BPASS = (BK * (BN / 4)) / 256;
#pragma unroll
        for (int p = 0; p < BPASS; ++p) {
            int id = p * 256 + tid;
            int kt = id / (BN / 4);
            int c4 = id % (BN / 4);
            float4 v = *(const float4*)(Bg + (size_t)(kb + kt) * N + n0 + c4 * 4);
            int g     = c4 >> 1;
            int hhalf = c4 & 1;
            int f     = (kt & 3) * 2 + hhalf;
            int slot  = f ^ (g & 7);
            Bs[(((kt >> 2) * NCG) + g) * 8 + slot] = v;
        }
        __syncthreads();

        for (int kk = 0; kk < BK / 4; ++kk) {
#pragma unroll
            for (int kq = 0; kq < 4; ++kq) {
                int k = kk * 4 + kq;
                float4 a0 = *(const float4*)(&As[k * BMP + r0]);
                float4 a1 = *(const float4*)(&As[k * BMP + r0 + 4]);
                float4 b0 = Bs[(kk * NCG + tc) * 8 + ((kq * 2 + 0) ^ (tc & 7))];
                float4 b1 = Bs[(kk * NCG + tc) * 8 + ((kq * 2 + 1) ^ (tc & 7))];
                float av[8] = {a0.x, a0.y, a0.z, a0.w, a1.x, a1.y, a1.z, a1.w};
                float bv[8] = {b0.x, b0.y, b0.z, b0.w, b1.x, b1.y, b1.z, b1.w};
#pragma unroll
                for (int i = 0; i < 8; ++i)
#pragma unroll
                    for (int j = 0; j < 8; ++j) acc[i][j] += av[i] * bv[j];
            }
        }
        __syncthreads();
    }

    // epilogue: store C + alpha dot (shuffle-reduced across the GRP lanes of a head)
    const int cb   = n0 + tc * 8;
    const int head = cb / CPH;
    const int ci0  = cb % CPH;
    float asv[8], adv[8];
#pragma unroll
    for (int j = 0; j < 8; ++j) {
        asv[j] = avec_s[head * CPH + ci0 + j];
        adv[j] = avec_d[head * CPH + ci0 + j];
    }
#pragma unroll
    for (int i = 0; i < 8; ++i) {
        int row = m0 + r0 + i;
        float ps = 0.f, pd = 0.f;
#pragma unroll
        for (int j = 0; j < 8; ++j) {
            ps += acc[i][j] * asv[j];
            pd += acc[i][j] * adv[j];
        }
#pragma unroll
        for (int d = GRP / 2; d >= 1; d >>= 1) {
            ps += __shfl_down(ps, d);
            pd += __shfl_down(pd, d);
        }
        if (row < M) {
            float4 c0 = make_float4(acc[i][0], acc[i][1], acc[i][2], acc[i][3]);
            float4 c1 = make_float4(acc[i][4], acc[i][5], acc[i][6], acc[i][7]);
            *(float4*)(C + (size_t)row * N + cb)     = c0;
            *(float4*)(C + (size_t)row * N + cb + 4) = c1;
            if ((tc & (GRP - 1)) == 0) {
                alpha_s[row * HEADS + head] = ps;
                alpha_d[row * HEADS + head] = pd;
            }
        }
    }
}

// ---------------- CSR build ----------------
__global__ void count_kernel(const int* __restrict__ dst, int* __restrict__ counts, int E)
{
    int e = blockIdx.x * 256 + threadIdx.x;
    if (e < E) atomicAdd(&counts[dst[e]], 1);
}

__global__ void scatter_kernel(const int* __restrict__ src, const int* __restrict__ dst,
                               int* __restrict__ cursor, int* __restrict__ csr, int E)
{
    int e = blockIdx.x * 256 + threadIdx.x;
    if (e < E) {
        int d   = dst[e];
        int pos = atomicAdd(&cursor[d], 1);
        csr[pos] = src[e];
    }
}

// single-block exclusive scan over n counts -> row_ptr[0..n], cursor copy
__global__ __launch_bounds__(1024)
void scan_kernel(const int* __restrict__ counts, int* __restrict__ row_ptr,
                 int* __restrict__ cursor, int n)
{
    __shared__ int wsum[16];
    __shared__ int running;
    const int t = threadIdx.x, lane = t & 63, w = t >> 6;
    if (t == 0) running = 0;
    __syncthreads();
    for (int base = 0; base < n; base += 1024) {
        int i = base + t;
        int v = (i < n) ? counts[i] : 0;
        int x = v;
#pragma unroll
        for (int d = 1; d < 64; d <<= 1) {
            int y = __shfl_up(x, d);
            if (lane >= d) x += y;
        }
        if (lane == 63) wsum[w] = x;
        __syncthreads();
        if (t < 16) {
            int s = wsum[t];
#pragma unroll
            for (int d = 1; d < 16; d <<= 1) {
                int y = __shfl_up(s, d);
                if (t >= d) s += y;
            }
            wsum[t] = s;
        }
        __syncthreads();
        int wbase = (w > 0) ? wsum[w - 1] : 0;
        int excl  = running + wbase + x - v;
        if (i < n) {
            row_ptr[i] = excl;
            cursor[i]  = excl;
        }
        int total = wsum[15];
        __syncthreads();
        if (t == 0) running += total;
        __syncthreads();
    }
    if (t == 0) row_ptr[n] = running;
}

// ---------------- GAT softmax + aggregation ----------------
// one wave per destination node; includes PyG self-loop; writes relu(out + bias)
template<int CH>
__global__ __launch_bounds__(256)
void gat_agg(const float* __restrict__ h, const float* __restrict__ alpha_s,
             const float* __restrict__ alpha_d, const int* __restrict__ row_ptr,
             const int* __restrict__ csr_src, const float* __restrict__ bias,
             float* __restrict__ out, int n)
{
    const int wid  = threadIdx.x >> 6;
    const int lane = threadIdx.x & 63;
    const int node = blockIdx.x * 4 + wid;
    if (node >= n) return;
    const int head = lane >> 4;
    const int p0 = row_ptr[node], p1 = row_ptr[node + 1];
    const int deg = p1 - p0;

    const float4 asn = *(const float4*)(alpha_s + (size_t)node * 4);
    const float4 adn = *(const float4*)(alpha_d + (size_t)node * 4);
    float4 eself = f4lrelu(f4add(asn, adn));
    float4 m = eself;

    // pass 1: per-head max over incoming edges
    for (int ch = 0; ch < deg; ch += 64) {
        int cnt = min(64, deg - ch);
        int sl = (lane < cnt) ? csr_src[p0 + ch + lane] : 0;
        float4 al = *(const float4*)(alpha_s + (size_t)sl * 4);
        for (int j = 0; j < cnt; ++j) {
            float4 aj = shfl4(al, j);
            m = f4max(m, f4lrelu(f4add(aj, adn)));
        }
    }

    // pass 2: denom + unnormalized weighted sum (self-loop first)
    float4 den = f4exp(f4sub(eself, m));
    float  wse = pickh(den, head);
    float4 acc4 = make_float4(0.f, 0.f, 0.f, 0.f);
    float  acc1 = 0.f;
    if constexpr (CH == 256) {
        float4 hv = *(const float4*)(h + (size_t)node * CH + lane * 4);
        acc4 = make_float4(wse * hv.x, wse * hv.y, wse * hv.z, wse * hv.w);
    } else {
        acc1 = wse * h[(size_t)node * CH + lane];
    }
    for (int ch = 0; ch < deg; ch += 64) {
        int cnt = min(64, deg - ch);
        int sl = (lane < cnt) ? csr_src[p0 + ch + lane] : 0;
        float4 al = *(const float4*)(alpha_s + (size_t)sl * 4);
        for (int j = 0; j < cnt; ++j) {
            int    sj = __shfl(sl, j);
            float4 aj = shfl4(al, j);
            float4 w4 = f4exp(f4sub(f4lrelu(f4add(aj, adn)), m));
            den = f4add(den, w4);
            float w = pickh(w4, head);
            if constexpr (CH == 256) {
                float4 hv = *(const float4*)(h + (size_t)sj * CH + lane * 4);
                acc4.x += w * hv.x; acc4.y += w * hv.y;
                acc4.z += w * hv.z; acc4.w += w * hv.w;
            } else {
                acc1 += w * h[(size_t)sj * CH + lane];
            }
        }
    }

    float invd = 1.0f / (pickh(den, head) + 1e-16f);
    if constexpr (CH == 256) {
        int c0 = lane * 4;
        float4 o;
        o.x = fmaxf(acc4.x * invd + bias[c0 + 0], 0.f);
        o.y = fmaxf(acc4.y * invd + bias[c0 + 1], 0.f);
        o.z = fmaxf(acc4.z * invd + bias[c0 + 2], 0.f);
        o.w = fmaxf(acc4.w * invd + bias[c0 + 3], 0.f);
        *(float4*)(out + (size_t)node * CH + c0) = o;
    } else {
        out[(size_t)node * CH + lane] = fmaxf(acc1 * invd + bias[lane], 0.f);
    }
}

// ---------------- graph boundaries + fused mean-pool/FC ----------------
__global__ void graph_starts_kernel(const int* __restrict__ batch, int* __restrict__ starts,
                                    int n, int ngraphs)
{
    int g = threadIdx.x;
    if (g > ngraphs) return;
    int lo = 0, hi = n;
    while (lo < hi) {
        int mid = (lo + hi) >> 1;
        if (batch[mid] < g) lo = mid + 1; else hi = mid;
    }
    starts[g] = lo;
}

// one block per graph: segmented mean over sorted batch, then 2-wide FC
__global__ __launch_bounds__(256)
void pool_fc_kernel(const float* __restrict__ feat, const int* __restrict__ starts,
                    const float* __restrict__ Wfc, const float* __restrict__ bfc,
                    float* __restrict__ out)
{
    __shared__ float4 part[16][16];
    __shared__ float pooled[64];
    const int g = blockIdx.x;
    const int t = threadIdx.x;
    const int q = t & 15, ns = t >> 4;
    const int s0 = starts[g], s1 = starts[g + 1];
    float4 acc = make_float4(0.f, 0.f, 0.f, 0.f);
    for (int i = s0 + ns; i < s1; i += 16)
        acc = f4add(acc, *(const float4*)(feat + (size_t)i * 64 + q * 4));
    part[ns][q] = acc;
    __syncthreads();
    if (t < 16) {
        float4 s = part[0][t];
#pragma unroll
        for (int k = 1; k < 16; ++k) s = f4add(s, part[k][t]);
        float inv = 1.0f / fmaxf((float)(s1 - s0), 1.0f);
        pooled[t * 4 + 0] = s.x * inv;
        pooled[t * 4 + 1] = s.y * inv;
        pooled[t * 4 + 2] = s.z * inv;
        pooled[t * 4 + 3] = s.w * inv;
    }
    __syncthreads();
    if (t < 2) {
        float a = bfc[t];
        for (int c = 0; c < 64; ++c) a += pooled[c] * Wfc[c * 2 + t];
        out[g * 2 + t] = a;
    }
}

// ---------------- launch ----------------
extern "C" void kernel_launch(void* const* d_in, const int* in_sizes, int n_in,
                              void* d_out, int out_size, void* d_ws, size_t ws_size,
                              hipStream_t stream)
{
    const float* x    = (const float*)d_in[0];
    const int*   ei   = (const int*)d_in[1];
    const int*   batch= (const int*)d_in[2];
    const float* W1   = (const float*)d_in[3];
    const float* as1  = (const float*)d_in[4];
    const float* ad1  = (const float*)d_in[5];
    const float* b1   = (const float*)d_in[6];
    const float* W2   = (const float*)d_in[7];
    const float* as2  = (const float*)d_in[8];
    const float* ad2  = (const float*)d_in[9];
    const float* b2   = (const float*)d_in[10];
    const float* Wfc  = (const float*)d_in[11];
    const float* bfc  = (const float*)d_in[12];
    float* out = (float*)d_out;

    const int N = in_sizes[2];          // 50000 nodes
    const int E = in_sizes[1] / 27;     // 400000 edges
    const int F = in_sizes[0] / N;      // 128

    char* ws = (char*)d_ws;
    float* h1    = (float*)(ws + OFF_H1);
    float* out1  = (float*)(ws + OFF_OUT1);
    float* h2    = (float*)(ws + OFF_H1);              // reuse (h1 dead after agg1)
    float* out2  = (float*)(ws + OFF_H1 + 12800000);
    float* al_s  = (float*)(ws + OFF_AS);
    float* al_d  = (float*)(ws + OFF_AD);
    int*   rp    = (int*)(ws + OFF_RP);
    int*   cur   = (int*)(ws + OFF_CUR);
    int*   cnt   = (int*)(ws + OFF_CNT);
    int*   csr   = (int*)(ws + OFF_CSR);
    int*   strt  = (int*)(ws + OFF_STRT);

    const int egrid = (E + 255) / 256;

    // ---- layer 1 ----
    {
        dim3 g((N + 127) / 128, 256 / 128);
        gemm_gat<128, 128, 64><<<g, 256, 0, stream>>>(x, W1, h1, as1, ad1, al_s, al_d,
                                                      N, F, HEADS * 64);
    }
    hipMemsetAsync(cnt, 0, (size_t)N * sizeof(int), stream);
    count_kernel<<<egrid, 256, 0, stream>>>(ei + 26 * (size_t)E, cnt, E);
    scan_kernel<<<1, 1024, 0, stream>>>(cnt, rp, cur, N);
    scatter_kernel<<<egrid, 256, 0, stream>>>(ei + 17 * (size_t)E, ei + 26 * (size_t)E, cur, csr, E);
    gat_agg<256><<<(N + 3) / 4, 256, 0, stream>>>(h1, al_s, al_d, rp, csr, b1, out1, N);

    // ---- layer 2 ----
    {
        dim3 g((N + 255) / 256, 1);
        gemm_gat<256, 64, 16><<<g, 256, 0, stream>>>(out1, W2, h2, as2, ad2, al_s, al_d,
                                                     N, HEADS * 64, HEADS * 16);
    }
    hipMemsetAsync(cnt, 0, (size_t)N * sizeof(int), stream);
    count_kernel<<<egrid, 256, 0, stream>>>(ei + 16 * (size_t)E, cnt, E);
    scan_kernel<<<1, 1024, 0, stream>>>(cnt, rp, cur, N);
    scatter_kernel<<<egrid, 256, 0, stream>>>(ei + 15 * (size_t)E, ei + 16 * (size_t)E, cur, csr, E);
    gat_agg<64><<<(N + 3) / 4, 256, 0, stream>>>(h2, al_s, al_d, rp, csr, b2, out2, N);

    // ---- pool + fc ----
    graph_starts_kernel<<<1, 65, 0, stream>>>(batch, strt, N, 64);
    pool_fc_kernel<<<64, 256, 0, stream>>>(out2, strt, Wfc, bfc, out);
}

// Round 3
// 414.721 us; speedup vs baseline: 2.1096x; 1.0639x over previous
//
#include <hip/hip_runtime.h>
#include <math.h>

#define HEADS 4
#define NEG_SLOPE 0.2f

// ---------------- workspace layout (bytes) ----------------
static constexpr size_t OFF_H1   = 0;           // 51,200,000  (h1; later h2 + out2)
static constexpr size_t OFF_OUT1 = 51200000;    // 51,200,000
static constexpr size_t OFF_AS   = 102400000;   // 800,000
static constexpr size_t OFF_AD   = 103200000;   // 800,000
static constexpr size_t OFF_RP   = 104000000;   // 200,064 (row_ptr, N+1 ints)
static constexpr size_t OFF_CUR  = 104200064;   // 200,064 (cursor)
static constexpr size_t OFF_CNT  = 104400128;   // 200,064 (counts)
static constexpr size_t OFF_CSR  = 104600192;   // 1,600,000 (csr src ids)
static constexpr size_t OFF_STRT = 106200192;   // 260 (graph starts, 65 ints)

// ---------------- helpers ----------------
__device__ __forceinline__ float4 f4add(float4 a, float4 b) {
    return make_float4(a.x + b.x, a.y + b.y, a.z + b.z, a.w + b.w);
}
__device__ __forceinline__ float lrelu(float x) { return x > 0.f ? x : NEG_SLOPE * x; }
__device__ __forceinline__ float4 f4lrelu(float4 a) {
    return make_float4(lrelu(a.x), lrelu(a.y), lrelu(a.z), lrelu(a.w));
}
__device__ __forceinline__ float4 f4exp(float4 a) {
    return make_float4(__expf(a.x), __expf(a.y), __expf(a.z), __expf(a.w));
}
__device__ __forceinline__ float pickh(float4 v, int head) {
    float r = v.x;
    r = head == 1 ? v.y : r;
    r = head == 2 ? v.z : r;
    r = head == 3 ? v.w : r;
    return r;
}

// ---------------- GEMM with GAT-alpha epilogue ----------------
// C[M,N] = A[M,K] @ B[K,N]; alpha_{s,d}[m,h] = sum_c C[m,h*CPH+c]*avec_{s,d}[h,c]
template<int BM, int BN, int CPH>
__global__ __launch_bounds__(256, 2)
void gemm_gat(const float* __restrict__ A, const float* __restrict__ Bg,
              float* __restrict__ C,
              const float* __restrict__ avec_s, const float* __restrict__ avec_d,
              float* __restrict__ alpha_s, float* __restrict__ alpha_d,
              int M, int K, int N)
{
    constexpr int BK  = 32;
    constexpr int BMP = BM + 4;
    constexpr int NCG = BN / 8;   // 8-col groups
    constexpr int NTC = BN / 8;
    constexpr int GRP = CPH / 8;  // threads per (row,head)
    static_assert((BM / 8) * (BN / 8) == 256, "thread mapping");

    __shared__ float  As[BK * BMP];
    __shared__ float4 Bs[(BK / 4) * NCG * 8];

    const int tid = threadIdx.x;
    const int tr  = tid / NTC;
    const int tc  = tid % NTC;
    const int m0  = blockIdx.x * BM;
    const int n0  = blockIdx.y * BN;
    const int r0  = tr * 8;

    float acc[8][8];
#pragma unroll
    for (int i = 0; i < 8; ++i)
#pragma unroll
        for (int j = 0; j < 8; ++j) acc[i][j] = 0.f;

    for (int kb = 0; kb < K; kb += BK) {
        constexpr int APASS = (BM * (BK / 4)) / 256;
#pragma unroll
        for (int p = 0; p < APASS; ++p) {
            int id  = p * 256 + tid;
            int mt  = id / (BK / 4);
            int kq4 = (id % (BK / 4)) * 4;
            int row = m0 + mt;
            row = row < M ? row : M - 1;
            float4 v = *(const float4*)(A + (size_t)row * K + kb + kq4);
            As[(kq4 + 0) * BMP + mt] = v.x;
            As[(kq4 + 1) * BMP + mt] = v.y;
            As[(kq4 + 2) * BMP + mt] = v.z;
            As[(kq4 + 3) * BMP + mt] = v.w;
        }
        constexpr int BPASS = (BK * (BN / 4)) / 256;
#pragma unroll
        for (int p = 0; p < BPASS; ++p) {
            int id = p * 256 + tid;
            int kt = id / (BN / 4);
            int c4 = id % (BN / 4);
            float4 v = *(const float4*)(Bg + (size_t)(kb + kt) * N + n0 + c4 * 4);
            int g     = c4 >> 1;
            int hhalf = c4 & 1;
            int f     = (kt & 3) * 2 + hhalf;
            int slot  = f ^ (g & 7);
            Bs[(((kt >> 2) * NCG) + g) * 8 + slot] = v;
        }
        __syncthreads();

        for (int kk = 0; kk < BK / 4; ++kk) {
#pragma unroll
            for (int kq = 0; kq < 4; ++kq) {
                int k = kk * 4 + kq;
                float4 a0 = *(const float4*)(&As[k * BMP + r0]);
                float4 a1 = *(const float4*)(&As[k * BMP + r0 + 4]);
                float4 b0 = Bs[(kk * NCG + tc) * 8 + ((kq * 2 + 0) ^ (tc & 7))];
                float4 b1 = Bs[(kk * NCG + tc) * 8 + ((kq * 2 + 1) ^ (tc & 7))];
                float av[8] = {a0.x, a0.y, a0.z, a0.w, a1.x, a1.y, a1.z, a1.w};
                float bv[8] = {b0.x, b0.y, b0.z, b0.w, b1.x, b1.y, b1.z, b1.w};
#pragma unroll
                for (int i = 0; i < 8; ++i)
#pragma unroll
                    for (int j = 0; j < 8; ++j) acc[i][j] += av[i] * bv[j];
            }
        }
        __syncthreads();
    }

    const int cb   = n0 + tc * 8;
    const int head = cb / CPH;
    const int ci0  = cb % CPH;
    float asv[8], adv[8];
#pragma unroll
    for (int j = 0; j < 8; ++j) {
        asv[j] = avec_s[head * CPH + ci0 + j];
        adv[j] = avec_d[head * CPH + ci0 + j];
    }
#pragma unroll
    for (int i = 0; i < 8; ++i) {
        int row = m0 + r0 + i;
        float ps = 0.f, pd = 0.f;
#pragma unroll
        for (int j = 0; j < 8; ++j) {
            ps += acc[i][j] * asv[j];
            pd += acc[i][j] * adv[j];
        }
#pragma unroll
        for (int d = GRP / 2; d >= 1; d >>= 1) {
            ps += __shfl_down(ps, d);
            pd += __shfl_down(pd, d);
        }
        if (row < M) {
            float4 c0 = make_float4(acc[i][0], acc[i][1], acc[i][2], acc[i][3]);
            float4 c1 = make_float4(acc[i][4], acc[i][5], acc[i][6], acc[i][7]);
            *(float4*)(C + (size_t)row * N + cb)     = c0;
            *(float4*)(C + (size_t)row * N + cb + 4) = c1;
            if ((tc & (GRP - 1)) == 0) {
                alpha_s[row * HEADS + head] = ps;
                alpha_d[row * HEADS + head] = pd;
            }
        }
    }
}

// ---------------- CSR build ----------------
__global__ void count_kernel(const int* __restrict__ dst, int* __restrict__ counts, int E)
{
    int e = blockIdx.x * 256 + threadIdx.x;
    if (e < E) atomicAdd(&counts[dst[e]], 1);
}

__global__ void scatter_kernel(const int* __restrict__ src, const int* __restrict__ dst,
                               int* __restrict__ cursor, int* __restrict__ csr, int E)
{
    int e = blockIdx.x * 256 + threadIdx.x;
    if (e < E) {
        int d   = dst[e];
        int pos = atomicAdd(&cursor[d], 1);
        csr[pos] = src[e];
    }
}

// single-block exclusive scan over n counts -> row_ptr[0..n], cursor copy
__global__ __launch_bounds__(1024)
void scan_kernel(const int* __restrict__ counts, int* __restrict__ row_ptr,
                 int* __restrict__ cursor, int n)
{
    __shared__ int wsum[16];
    __shared__ int running;
    const int t = threadIdx.x, lane = t & 63, w = t >> 6;
    if (t == 0) running = 0;
    __syncthreads();
    for (int base = 0; base < n; base += 1024) {
        int i = base + t;
        int v = (i < n) ? counts[i] : 0;
        int x = v;
#pragma unroll
        for (int d = 1; d < 64; d <<= 1) {
            int y = __shfl_up(x, d);
            if (lane >= d) x += y;
        }
        if (lane == 63) wsum[w] = x;
        __syncthreads();
        if (t < 16) {
            int s = wsum[t];
#pragma unroll
            for (int d = 1; d < 16; d <<= 1) {
                int y = __shfl_up(s, d);
                if (t >= d) s += y;
            }
            wsum[t] = s;
        }
        __syncthreads();
        int wbase = (w > 0) ? wsum[w - 1] : 0;
        int excl  = running + wbase + x - v;
        if (i < n) {
            row_ptr[i] = excl;
            cursor[i]  = excl;
        }
        int total = wsum[15];
        __syncthreads();
        if (t == 0) running += total;
        __syncthreads();
    }
    if (t == 0) row_ptr[n] = running;
}

// ---------------- GAT softmax + aggregation ----------------
// One wave per destination node. No max-shift: softmax is shift-invariant and
// |e| is O(1) here, far from f32 exp range limits (+-88).
// Phase A (per 64-edge chunk): lane j computes edge j's 4-head weight ONCE,
// butterfly-sum for the denominator, stash (src, w4) in per-wave LDS.
// Phase B: per edge, 2 broadcast ds_reads + coalesced h-row load + FMA.
template<int CH>
__global__ __launch_bounds__(256)
void gat_agg(const float* __restrict__ h, const float* __restrict__ alpha_s,
             const float* __restrict__ alpha_d, const int* __restrict__ row_ptr,
             const int* __restrict__ csr_src, const float* __restrict__ bias,
             float* __restrict__ out, int n)
{
    __shared__ float wls[4][64 * 5];   // [wave][j*5+h] stride-5: conflict-free write/read
    __shared__ int   sls[4][64];
    const int wid  = threadIdx.x >> 6;
    const int lane = threadIdx.x & 63;
    const int node = blockIdx.x * 4 + wid;
    if (node >= n) return;
    const int head = lane >> 4;        // CH=256: c0=lane*4, head=c0/64; CH=64: c=lane, head=c/16
    const int p0 = row_ptr[node], p1 = row_ptr[node + 1];
    const int deg = p1 - p0;

    const float4 asn = *(const float4*)(alpha_s + (size_t)node * 4);
    const float4 adn = *(const float4*)(alpha_d + (size_t)node * 4);
    float4 den = f4exp(f4lrelu(f4add(asn, adn)));   // self-loop term
    const float wse = pickh(den, head);

    float4 acc4 = make_float4(0.f, 0.f, 0.f, 0.f);
    float  acc1 = 0.f;
    if constexpr (CH == 256) {
        float4 hv = *(const float4*)(h + (size_t)node * CH + lane * 4);
        acc4 = make_float4(wse * hv.x, wse * hv.y, wse * hv.z, wse * hv.w);
    } else {
        acc1 = wse * h[(size_t)node * CH + lane];
    }

    for (int ch = 0; ch < deg; ch += 64) {
        const int cnt = min(64, deg - ch);
        float4 w4 = make_float4(0.f, 0.f, 0.f, 0.f);
        int sl = 0;
        if (lane < cnt) {
            sl = csr_src[p0 + ch + lane];
            float4 al = *(const float4*)(alpha_s + (size_t)sl * 4);
            w4 = f4exp(f4lrelu(f4add(al, adn)));
        }
        // denominator: butterfly sum (inactive lanes contribute 0)
        float4 t = w4;
#pragma unroll
        for (int d = 32; d >= 1; d >>= 1) {
            t.x += __shfl_xor(t.x, d);
            t.y += __shfl_xor(t.y, d);
            t.z += __shfl_xor(t.z, d);
            t.w += __shfl_xor(t.w, d);
        }
        den = f4add(den, t);
        // stash weights + src ids (same-wave LDS: no block barrier needed)
        sls[wid][lane] = sl;
        wls[wid][lane * 5 + 0] = w4.x;
        wls[wid][lane * 5 + 1] = w4.y;
        wls[wid][lane * 5 + 2] = w4.z;
        wls[wid][lane * 5 + 3] = w4.w;

        for (int j = 0; j < cnt; ++j) {
            int   sj = sls[wid][j];
            float w  = wls[wid][j * 5 + head];
            if constexpr (CH == 256) {
                float4 hv = *(const float4*)(h + (size_t)sj * CH + lane * 4);
                acc4.x += w * hv.x; acc4.y += w * hv.y;
                acc4.z += w * hv.z; acc4.w += w * hv.w;
            } else {
                acc1 += w * h[(size_t)sj * CH + lane];
            }
        }
    }

    const float invd = 1.0f / (pickh(den, head) + 1e-16f);
    if constexpr (CH == 256) {
        int c0 = lane * 4;
        float4 o;
        o.x = fmaxf(acc4.x * invd + bias[c0 + 0], 0.f);
        o.y = fmaxf(acc4.y * invd + bias[c0 + 1], 0.f);
        o.z = fmaxf(acc4.z * invd + bias[c0 + 2], 0.f);
        o.w = fmaxf(acc4.w * invd + bias[c0 + 3], 0.f);
        *(float4*)(out + (size_t)node * CH + c0) = o;
    } else {
        out[(size_t)node * CH + lane] = fmaxf(acc1 * invd + bias[lane], 0.f);
    }
}

// ---------------- graph boundaries + fused mean-pool/FC ----------------
__global__ void graph_starts_kernel(const int* __restrict__ batch, int* __restrict__ starts,
                                    int n, int ngraphs)
{
    int g = threadIdx.x;
    if (g > ngraphs) return;
    int lo = 0, hi = n;
    while (lo < hi) {
        int mid = (lo + hi) >> 1;
        if (batch[mid] < g) lo = mid + 1; else hi = mid;
    }
    starts[g] = lo;
}

__global__ __launch_bounds__(256)
void pool_fc_kernel(const float* __restrict__ feat, const int* __restrict__ starts,
                    const float* __restrict__ Wfc, const float* __restrict__ bfc,
                    float* __restrict__ out)
{
    __shared__ float4 part[16][16];
    __shared__ float pooled[64];
    const int g = blockIdx.x;
    const int t = threadIdx.x;
    const int q = t & 15, ns = t >> 4;
    const int s0 = starts[g], s1 = starts[g + 1];
    float4 acc = make_float4(0.f, 0.f, 0.f, 0.f);
    for (int i = s0 + ns; i < s1; i += 16)
        acc = f4add(acc, *(const float4*)(feat + (size_t)i * 64 + q * 4));
    part[ns][q] = acc;
    __syncthreads();
    if (t < 16) {
        float4 s = part[0][t];
#pragma unroll
        for (int k = 1; k < 16; ++k) s = f4add(s, part[k][t]);
        float inv = 1.0f / fmaxf((float)(s1 - s0), 1.0f);
        pooled[t * 4 + 0] = s.x * inv;
        pooled[t * 4 + 1] = s.y * inv;
        pooled[t * 4 + 2] = s.z * inv;
        pooled[t * 4 + 3] = s.w * inv;
    }
    __syncthreads();
    if (t < 2) {
        float a = bfc[t];
        for (int c = 0; c < 64; ++c) a += pooled[c] * Wfc[c * 2 + t];
        out[g * 2 + t] = a;
    }
}

// ---------------- launch ----------------
extern "C" void kernel_launch(void* const* d_in, const int* in_sizes, int n_in,
                              void* d_out, int out_size, void* d_ws, size_t ws_size,
                              hipStream_t stream)
{
    const float* x    = (const float*)d_in[0];
    const int*   ei   = (const int*)d_in[1];
    const int*   batch= (const int*)d_in[2];
    const float* W1   = (const float*)d_in[3];
    const float* as1  = (const float*)d_in[4];
    const float* ad1  = (const float*)d_in[5];
    const float* b1   = (const float*)d_in[6];
    const float* W2   = (const float*)d_in[7];
    const float* as2  = (const float*)d_in[8];
    const float* ad2  = (const float*)d_in[9];
    const float* b2   = (const float*)d_in[10];
    const float* Wfc  = (const float*)d_in[11];
    const float* bfc  = (const float*)d_in[12];
    float* out = (float*)d_out;

    const int N = in_sizes[2];          // 50000 nodes
    const int E = in_sizes[1] / 27;     // 400000 edges
    const int F = in_sizes[0] / N;      // 128

    char* ws = (char*)d_ws;
    float* h1    = (float*)(ws + OFF_H1);
    float* out1  = (float*)(ws + OFF_OUT1);
    float* h2    = (float*)(ws + OFF_H1);              // reuse (h1 dead after agg1)
    float* out2  = (float*)(ws + OFF_H1 + 12800000);
    float* al_s  = (float*)(ws + OFF_AS);
    float* al_d  = (float*)(ws + OFF_AD);
    int*   rp    = (int*)(ws + OFF_RP);
    int*   cur   = (int*)(ws + OFF_CUR);
    int*   cnt   = (int*)(ws + OFF_CNT);
    int*   csr   = (int*)(ws + OFF_CSR);
    int*   strt  = (int*)(ws + OFF_STRT);

    const int egrid = (E + 255) / 256;

    // ---- layer 1 ----
    {
        dim3 g((N + 127) / 128, 256 / 128);
        gemm_gat<128, 128, 64><<<g, 256, 0, stream>>>(x, W1, h1, as1, ad1, al_s, al_d,
                                                      N, F, HEADS * 64);
    }
    hipMemsetAsync(cnt, 0, (size_t)N * sizeof(int), stream);
    count_kernel<<<egrid, 256, 0, stream>>>(ei + 26 * (size_t)E, cnt, E);
    scan_kernel<<<1, 1024, 0, stream>>>(cnt, rp, cur, N);
    scatter_kernel<<<egrid, 256, 0, stream>>>(ei + 17 * (size_t)E, ei + 26 * (size_t)E, cur, csr, E);
    gat_agg<256><<<(N + 3) / 4, 256, 0, stream>>>(h1, al_s, al_d, rp, csr, b1, out1, N);

    // ---- layer 2 ----
    {
        dim3 g((N + 255) / 256, 1);
        gemm_gat<256, 64, 16><<<g, 256, 0, stream>>>(out1, W2, h2, as2, ad2, al_s, al_d,
                                                     N, HEADS * 64, HEADS * 16);
    }
    hipMemsetAsync(cnt, 0, (size_t)N * sizeof(int), stream);
    count_kernel<<<egrid, 256, 0, stream>>>(ei + 16 * (size_t)E, cnt, E);
    scan_kernel<<<1, 1024, 0, stream>>>(cnt, rp, cur, N);
    scatter_kernel<<<egrid, 256, 0, stream>>>(ei + 15 * (size_t)E, ei + 16 * (size_t)E, cur, csr, E);
    gat_agg<64><<<(N + 3) / 4, 256, 0, stream>>>(h2, al_s, al_d, rp, csr, b2, out2, N);

    // ---- pool + fc ----
    graph_starts_kernel<<<1, 65, 0, stream>>>(batch, strt, N, 64);
    pool_fc_kernel<<<64, 256, 0, stream>>>(out2, strt, Wfc, bfc, out);
}

// Round 4
// 335.713 us; speedup vs baseline: 2.6061x; 1.2353x over previous
//
#include <hip/hip_runtime.h>
#include <math.h>

#define HEADS 4
#define NEG_SLOPE 0.2f

// ---------------- workspace layout (bytes) ----------------
static constexpr size_t OFF_H1   = 0;           // 51,200,000  (h1; later h2 + out2)
static constexpr size_t OFF_OUT1 = 51200000;    // 51,200,000
static constexpr size_t OFF_AS   = 102400000;   // 800,000
static constexpr size_t OFF_AD   = 103200000;   // 800,000
static constexpr size_t OFF_RP   = 104000000;   // 200,064 (row_ptr, N+1 ints)
static constexpr size_t OFF_CUR  = 104200064;   // 200,064 (cursor)
static constexpr size_t OFF_CNT  = 104400128;   // 200,064 (counts)
static constexpr size_t OFF_CSR  = 104600192;   // 1,600,000 (csr src ids)
static constexpr size_t OFF_STRT = 106200192;   // 260 (graph starts, 65 ints)
static constexpr size_t OFF_BSUM = 106200704;   // 256 (block sums for scan)
static constexpr size_t OFF_BOFF = 106201216;   // 256 (block offsets for scan)

// ---------------- helpers ----------------
__device__ __forceinline__ float4 f4add(float4 a, float4 b) {
    return make_float4(a.x + b.x, a.y + b.y, a.z + b.z, a.w + b.w);
}
__device__ __forceinline__ float lrelu(float x) { return x > 0.f ? x : NEG_SLOPE * x; }
__device__ __forceinline__ float4 f4lrelu(float4 a) {
    return make_float4(lrelu(a.x), lrelu(a.y), lrelu(a.z), lrelu(a.w));
}
__device__ __forceinline__ float4 f4exp(float4 a) {
    return make_float4(__expf(a.x), __expf(a.y), __expf(a.z), __expf(a.w));
}
__device__ __forceinline__ float pickh(float4 v, int head) {
    float r = v.x;
    r = head == 1 ? v.y : r;
    r = head == 2 ? v.z : r;
    r = head == 3 ? v.w : r;
    return r;
}

// ---------------- GEMM with GAT-alpha epilogue ----------------
// C[M,N] = A[M,K] @ B[K,N]; alpha_{s,d}[m,h] = sum_c C[m,h*CPH+c]*avec_{s,d}[h,c]
// As: flat [BK][BM] with float4-group XOR swizzle g' = (m>>2) ^ (k>>2):
//   stores spread 64 lanes over all 32 banks (2-way = free), float4 reads stay
//   aligned, 4 distinct bank groups x 16-lane broadcast (conflict-free).
// K-loop: register-prefetch pipeline (issue tile t+1 global loads under
// compute of tile t).
template<int BM, int BN, int CPH>
__global__ __launch_bounds__(256, 2)
void gemm_gat(const float* __restrict__ A, const float* __restrict__ Bg,
              float* __restrict__ C,
              const float* __restrict__ avec_s, const float* __restrict__ avec_d,
              float* __restrict__ alpha_s, float* __restrict__ alpha_d,
              int M, int K, int N)
{
    constexpr int BK    = 32;
    constexpr int NCG   = BN / 8;   // 8-col groups
    constexpr int NTC   = BN / 8;
    constexpr int GRP   = CPH / 8;  // threads per (row,head)
    constexpr int APASS = (BM * (BK / 4)) / 256;
    constexpr int BPASS = (BK * (BN / 4)) / 256;
    static_assert((BM / 8) * (BN / 8) == 256, "thread mapping");

    __shared__ float  As[BK * BM];
    __shared__ float4 Bs[(BK / 4) * NCG * 8];

    const int tid = threadIdx.x;
    const int tr  = tid / NTC;
    const int tc  = tid % NTC;
    const int m0  = blockIdx.x * BM;
    const int n0  = blockIdx.y * BN;

    float acc[8][8];
#pragma unroll
    for (int i = 0; i < 8; ++i)
#pragma unroll
        for (int j = 0; j < 8; ++j) acc[i][j] = 0.f;

    float4 aReg[APASS];
    float4 bReg[BPASS];

    auto LOAD = [&](int kb) {
#pragma unroll
        for (int p = 0; p < APASS; ++p) {
            int id  = p * 256 + tid;
            int mt  = id / (BK / 4);
            int kq4 = (id % (BK / 4)) * 4;
            int row = m0 + mt;
            row = row < M ? row : M - 1;
            aReg[p] = *(const float4*)(A + (size_t)row * K + kb + kq4);
        }
#pragma unroll
        for (int p = 0; p < BPASS; ++p) {
            int id = p * 256 + tid;
            int kt = id / (BN / 4);
            int c4 = id % (BN / 4);
            bReg[p] = *(const float4*)(Bg + (size_t)(kb + kt) * N + n0 + c4 * 4);
        }
    };

    auto STORE = [&]() {
#pragma unroll
        for (int p = 0; p < APASS; ++p) {
            int id  = p * 256 + tid;
            int mt  = id / (BK / 4);
            int p8  = id % (BK / 4);        // = k>>2 for this thread's 4 k's
            int kq4 = p8 * 4;
            int gsw = (mt >> 2) ^ p8;       // swizzled float4 group
            int lo  = mt & 3;
            float vv[4] = {aReg[p].x, aReg[p].y, aReg[p].z, aReg[p].w};
#pragma unroll
            for (int j = 0; j < 4; ++j)
                As[(kq4 + j) * BM + 4 * gsw + lo] = vv[j];
        }
#pragma unroll
        for (int p = 0; p < BPASS; ++p) {
            int id = p * 256 + tid;
            int kt = id / (BN / 4);
            int c4 = id % (BN / 4);
            int g     = c4 >> 1;
            int hhalf = c4 & 1;
            int f     = (kt & 3) * 2 + hhalf;
            int slot  = f ^ (g & 7);
            Bs[(((kt >> 2) * NCG) + g) * 8 + slot] = bReg[p];
        }
    };

    const int NT = K / BK;
    LOAD(0);
    for (int t = 0; t < NT; ++t) {
        STORE();
        __syncthreads();
        if (t + 1 < NT) LOAD((t + 1) * BK);   // issue next-tile loads under compute

        for (int kk = 0; kk < BK / 4; ++kk) {
#pragma unroll
            for (int kq = 0; kq < 4; ++kq) {
                int k  = kk * 4 + kq;
                int pk = kk;                   // (k>>2) for k<32
                float4 a0 = *(const float4*)(&As[k * BM + 4 * ((2 * tr)     ^ pk)]);
                float4 a1 = *(const float4*)(&As[k * BM + 4 * ((2 * tr + 1) ^ pk)]);
                float4 b0 = Bs[(kk * NCG + tc) * 8 + ((kq * 2 + 0) ^ (tc & 7))];
                float4 b1 = Bs[(kk * NCG + tc) * 8 + ((kq * 2 + 1) ^ (tc & 7))];
                float av[8] = {a0.x, a0.y, a0.z, a0.w, a1.x, a1.y, a1.z, a1.w};
                float bv[8] = {b0.x, b0.y, b0.z, b0.w, b1.x, b1.y, b1.z, b1.w};
#pragma unroll
                for (int i = 0; i < 8; ++i)
#pragma unroll
                    for (int j = 0; j < 8; ++j) acc[i][j] += av[i] * bv[j];
            }
        }
        __syncthreads();
    }

    const int cb   = n0 + tc * 8;
    const int head = cb / CPH;
    const int ci0  = cb % CPH;
    const int r0   = tr * 8;
    float asv[8], adv[8];
#pragma unroll
    for (int j = 0; j < 8; ++j) {
        asv[j] = avec_s[head * CPH + ci0 + j];
        adv[j] = avec_d[head * CPH + ci0 + j];
    }
#pragma unroll
    for (int i = 0; i < 8; ++i) {
        int row = m0 + r0 + i;
        float ps = 0.f, pd = 0.f;
#pragma unroll
        for (int j = 0; j < 8; ++j) {
            ps += acc[i][j] * asv[j];
            pd += acc[i][j] * adv[j];
        }
#pragma unroll
        for (int d = GRP / 2; d >= 1; d >>= 1) {
            ps += __shfl_down(ps, d);
            pd += __shfl_down(pd, d);
        }
        if (row < M) {
            float4 c0 = make_float4(acc[i][0], acc[i][1], acc[i][2], acc[i][3]);
            float4 c1 = make_float4(acc[i][4], acc[i][5], acc[i][6], acc[i][7]);
            *(float4*)(C + (size_t)row * N + cb)     = c0;
            *(float4*)(C + (size_t)row * N + cb + 4) = c1;
            if ((tc & (GRP - 1)) == 0) {
                alpha_s[row * HEADS + head] = ps;
                alpha_d[row * HEADS + head] = pd;
            }
        }
    }
}

// ---------------- CSR build ----------------
__global__ void count_kernel(const int* __restrict__ dst, int* __restrict__ counts, int E)
{
    int e = blockIdx.x * 256 + threadIdx.x;
    if (e < E) atomicAdd(&counts[dst[e]], 1);
}

__global__ void scatter_kernel(const int* __restrict__ src, const int* __restrict__ dst,
                               int* __restrict__ cursor, int* __restrict__ csr, int E)
{
    int e = blockIdx.x * 256 + threadIdx.x;
    if (e < E) {
        int d   = dst[e];
        int pos = atomicAdd(&cursor[d], 1);
        csr[pos] = src[e];
    }
}

// ---------------- parallel scan (3 kernels) ----------------
// 1) per-1024-block exclusive scan -> row_ptr (local), block totals -> bsum
__global__ __launch_bounds__(1024)
void scan_block_kernel(const int* __restrict__ counts, int* __restrict__ excl_out,
                       int* __restrict__ bsum, int n)
{
    __shared__ int wsum[16];
    const int t = threadIdx.x, lane = t & 63, w = t >> 6;
    const int i = blockIdx.x * 1024 + t;
    int v = (i < n) ? counts[i] : 0;
    int x = v;
#pragma unroll
    for (int d = 1; d < 64; d <<= 1) {
        int y = __shfl_up(x, d);
        if (lane >= d) x += y;
    }
    if (lane == 63) wsum[w] = x;
    __syncthreads();
    if (t < 16) {
        int s = wsum[t];
#pragma unroll
        for (int d = 1; d < 16; d <<= 1) {
            int y = __shfl_up(s, d);
            if (t >= d) s += y;
        }
        wsum[t] = s;
    }
    __syncthreads();
    int wbase = (w > 0) ? wsum[w - 1] : 0;
    if (i < n) excl_out[i] = wbase + x - v;
    if (t == 1023) bsum[blockIdx.x] = wsum[15];
}

// 2) single-wave scan of block totals (nb <= 64); also writes row_ptr[n] = total
__global__ void scan_tops_kernel(const int* __restrict__ bsum, int* __restrict__ boff,
                                 int* __restrict__ row_ptr, int nb, int n)
{
    const int t = threadIdx.x;   // 64 threads, one wave
    int v = (t < nb) ? bsum[t] : 0;
    int x = v;
#pragma unroll
    for (int d = 1; d < 64; d <<= 1) {
        int y = __shfl_up(x, d);
        if (t >= d) x += y;
    }
    if (t < nb) boff[t] = x - v;
    if (t == 63) row_ptr[n] = x;
}

// 3) add block offsets; produce final row_ptr + cursor copy
__global__ __launch_bounds__(1024)
void scan_add_kernel(const int* __restrict__ boff, int* __restrict__ row_ptr,
                     int* __restrict__ cursor, int n)
{
    const int i = blockIdx.x * 1024 + threadIdx.x;
    if (i < n) {
        int r = row_ptr[i] + boff[blockIdx.x];
        row_ptr[i] = r;
        cursor[i]  = r;
    }
}

// ---------------- GAT softmax + aggregation ----------------
// One wave per destination node. No max-shift: softmax is shift-invariant and
// |e| is O(1) here, far from f32 exp range limits (+-88).
template<int CH>
__global__ __launch_bounds__(256)
void gat_agg(const float* __restrict__ h, const float* __restrict__ alpha_s,
             const float* __restrict__ alpha_d, const int* __restrict__ row_ptr,
             const int* __restrict__ csr_src, const float* __restrict__ bias,
             float* __restrict__ out, int n)
{
    __shared__ float wls[4][64 * 5];   // [wave][j*5+h] stride-5: conflict-free
    __shared__ int   sls[4][64];
    const int wid  = threadIdx.x >> 6;
    const int lane = threadIdx.x & 63;
    const int node = blockIdx.x * 4 + wid;
    if (node >= n) return;
    const int head = lane >> 4;
    const int p0 = row_ptr[node], p1 = row_ptr[node + 1];
    const int deg = p1 - p0;

    const float4 asn = *(const float4*)(alpha_s + (size_t)node * 4);
    const float4 adn = *(const float4*)(alpha_d + (size_t)node * 4);
    float4 den = f4exp(f4lrelu(f4add(asn, adn)));   // self-loop term
    const float wse = pickh(den, head);

    float4 acc4 = make_float4(0.f, 0.f, 0.f, 0.f);
    float  acc1 = 0.f;
    if constexpr (CH == 256) {
        float4 hv = *(const float4*)(h + (size_t)node * CH + lane * 4);
        acc4 = make_float4(wse * hv.x, wse * hv.y, wse * hv.z, wse * hv.w);
    } else {
        acc1 = wse * h[(size_t)node * CH + lane];
    }

    for (int ch = 0; ch < deg; ch += 64) {
        const int cnt = min(64, deg - ch);
        float4 w4 = make_float4(0.f, 0.f, 0.f, 0.f);
        int sl = 0;
        if (lane < cnt) {
            sl = csr_src[p0 + ch + lane];
            float4 al = *(const float4*)(alpha_s + (size_t)sl * 4);
            w4 = f4exp(f4lrelu(f4add(al, adn)));
        }
        float4 t = w4;
#pragma unroll
        for (int d = 32; d >= 1; d >>= 1) {
            t.x += __shfl_xor(t.x, d);
            t.y += __shfl_xor(t.y, d);
            t.z += __shfl_xor(t.z, d);
            t.w += __shfl_xor(t.w, d);
        }
        den = f4add(den, t);
        sls[wid][lane] = sl;
        wls[wid][lane * 5 + 0] = w4.x;
        wls[wid][lane * 5 + 1] = w4.y;
        wls[wid][lane * 5 + 2] = w4.z;
        wls[wid][lane * 5 + 3] = w4.w;

        for (int j = 0; j < cnt; ++j) {
            int   sj = sls[wid][j];
            float w  = wls[wid][j * 5 + head];
            if constexpr (CH == 256) {
                float4 hv = *(const float4*)(h + (size_t)sj * CH + lane * 4);
                acc4.x += w * hv.x; acc4.y += w * hv.y;
                acc4.z += w * hv.z; acc4.w += w * hv.w;
            } else {
                acc1 += w * h[(size_t)sj * CH + lane];
            }
        }
    }

    const float invd = 1.0f / (pickh(den, head) + 1e-16f);
    if constexpr (CH == 256) {
        int c0 = lane * 4;
        float4 o;
        o.x = fmaxf(acc4.x * invd + bias[c0 + 0], 0.f);
        o.y = fmaxf(acc4.y * invd + bias[c0 + 1], 0.f);
        o.z = fmaxf(acc4.z * invd + bias[c0 + 2], 0.f);
        o.w = fmaxf(acc4.w * invd + bias[c0 + 3], 0.f);
        *(float4*)(out + (size_t)node * CH + c0) = o;
    } else {
        out[(size_t)node * CH + lane] = fmaxf(acc1 * invd + bias[lane], 0.f);
    }
}

// ---------------- graph boundaries + fused mean-pool/FC ----------------
__global__ void graph_starts_kernel(const int* __restrict__ batch, int* __restrict__ starts,
                                    int n, int ngraphs)
{
    int g = threadIdx.x;
    if (g > ngraphs) return;
    int lo = 0, hi = n;
    while (lo < hi) {
        int mid = (lo + hi) >> 1;
        if (batch[mid] < g) lo = mid + 1; else hi = mid;
    }
    starts[g] = lo;
}

__global__ __launch_bounds__(256)
void pool_fc_kernel(const float* __restrict__ feat, const int* __restrict__ starts,
                    const float* __restrict__ Wfc, const float* __restrict__ bfc,
                    float* __restrict__ out)
{
    __shared__ float4 part[16][16];
    __shared__ float pooled[64];
    const int g = blockIdx.x;
    const int t = threadIdx.x;
    const int q = t & 15, ns = t >> 4;
    const int s0 = starts[g], s1 = starts[g + 1];
    float4 acc = make_float4(0.f, 0.f, 0.f, 0.f);
    for (int i = s0 + ns; i < s1; i += 16)
        acc = f4add(acc, *(const float4*)(feat + (size_t)i * 64 + q * 4));
    part[ns][q] = acc;
    __syncthreads();
    if (t < 16) {
        float4 s = part[0][t];
#pragma unroll
        for (int k = 1; k < 16; ++k) s = f4add(s, part[k][t]);
        float inv = 1.0f / fmaxf((float)(s1 - s0), 1.0f);
        pooled[t * 4 + 0] = s.x * inv;
        pooled[t * 4 + 1] = s.y * inv;
        pooled[t * 4 + 2] = s.z * inv;
        pooled[t * 4 + 3] = s.w * inv;
    }
    __syncthreads();
    if (t < 2) {
        float a = bfc[t];
        for (int c = 0; c < 64; ++c) a += pooled[c] * Wfc[c * 2 + t];
        out[g * 2 + t] = a;
    }
}

// ---------------- launch ----------------
extern "C" void kernel_launch(void* const* d_in, const int* in_sizes, int n_in,
                              void* d_out, int out_size, void* d_ws, size_t ws_size,
                              hipStream_t stream)
{
    const float* x    = (const float*)d_in[0];
    const int*   ei   = (const int*)d_in[1];
    const int*   batch= (const int*)d_in[2];
    const float* W1   = (const float*)d_in[3];
    const float* as1  = (const float*)d_in[4];
    const float* ad1  = (const float*)d_in[5];
    const float* b1   = (const float*)d_in[6];
    const float* W2   = (const float*)d_in[7];
    const float* as2  = (const float*)d_in[8];
    const float* ad2  = (const float*)d_in[9];
    const float* b2   = (const float*)d_in[10];
    const float* Wfc  = (const float*)d_in[11];
    const float* bfc  = (const float*)d_in[12];
    float* out = (float*)d_out;

    const int N = in_sizes[2];          // 50000 nodes
    const int E = in_sizes[1] / 27;     // 400000 edges
    const int F = in_sizes[0] / N;      // 128

    char* ws = (char*)d_ws;
    float* h1    = (float*)(ws + OFF_H1);
    float* out1  = (float*)(ws + OFF_OUT1);
    float* h2    = (float*)(ws + OFF_H1);              // reuse (h1 dead after agg1)
    float* out2  = (float*)(ws + OFF_H1 + 12800000);
    float* al_s  = (float*)(ws + OFF_AS);
    float* al_d  = (float*)(ws + OFF_AD);
    int*   rp    = (int*)(ws + OFF_RP);
    int*   cur   = (int*)(ws + OFF_CUR);
    int*   cnt   = (int*)(ws + OFF_CNT);
    int*   csr   = (int*)(ws + OFF_CSR);
    int*   strt  = (int*)(ws + OFF_STRT);
    int*   bsum  = (int*)(ws + OFF_BSUM);
    int*   boff  = (int*)(ws + OFF_BOFF);

    const int egrid = (E + 255) / 256;
    const int NB    = (N + 1023) / 1024;   // scan blocks (49)

    // ---- layer 1 ----
    {
        dim3 g((N + 127) / 128, 256 / 128);
        gemm_gat<128, 128, 64><<<g, 256, 0, stream>>>(x, W1, h1, as1, ad1, al_s, al_d,
                                                      N, F, HEADS * 64);
    }
    hipMemsetAsync(cnt, 0, (size_t)N * sizeof(int), stream);
    count_kernel<<<egrid, 256, 0, stream>>>(ei + 26 * (size_t)E, cnt, E);
    scan_block_kernel<<<NB, 1024, 0, stream>>>(cnt, rp, bsum, N);
    scan_tops_kernel<<<1, 64, 0, stream>>>(bsum, boff, rp, NB, N);
    scan_add_kernel<<<NB, 1024, 0, stream>>>(boff, rp, cur, N);
    scatter_kernel<<<egrid, 256, 0, stream>>>(ei + 17 * (size_t)E, ei + 26 * (size_t)E, cur, csr, E);
    gat_agg<256><<<(N + 3) / 4, 256, 0, stream>>>(h1, al_s, al_d, rp, csr, b1, out1, N);

    // ---- layer 2 ----
    {
        dim3 g((N + 255) / 256, 1);
        gemm_gat<256, 64, 16><<<g, 256, 0, stream>>>(out1, W2, h2, as2, ad2, al_s, al_d,
                                                     N, HEADS * 64, HEADS * 16);
    }
    hipMemsetAsync(cnt, 0, (size_t)N * sizeof(int), stream);
    count_kernel<<<egrid, 256, 0, stream>>>(ei + 16 * (size_t)E, cnt, E);
    scan_block_kernel<<<NB, 1024, 0, stream>>>(cnt, rp, bsum, N);
    scan_tops_kernel<<<1, 64, 0, stream>>>(bsum, boff, rp, NB, N);
    scan_add_kernel<<<NB, 1024, 0, stream>>>(boff, rp, cur, N);
    scatter_kernel<<<egrid, 256, 0, stream>>>(ei + 15 * (size_t)E, ei + 16 * (size_t)E, cur, csr, E);
    gat_agg<64><<<(N + 3) / 4, 256, 0, stream>>>(h2, al_s, al_d, rp, csr, b2, out2, N);

    // ---- pool + fc ----
    graph_starts_kernel<<<1, 65, 0, stream>>>(batch, strt, N, 64);
    pool_fc_kernel<<<64, 256, 0, stream>>>(out2, strt, Wfc, bfc, out);
}